// Round 8
// baseline (111.205 us; speedup 1.0000x reference)
//
#include <hip/hip_runtime.h>
#include <cstdint>

#define B_ROWS   32768
#define D_DIM    512
#define NBLOCKS  512             // 2 blocks/CU exactly (LDS-capped), all resident
#define TPB      256             // 4 waves per block
#define WPB      (TPB / 64)
#define NWAVES   (NBLOCKS * WPB)          // 2048
#define RPW      (B_ROWS / NWAVES)        // 16 rows per wave, exact

struct Ws {
    unsigned anchor_idx;   // written by find_anchor
    int      done;         // init -1; last block sees old == NBLOCKS-2
};
// partials at (float*)d_ws + 64 : [NBLOCKS][12] (pos[4], neg[4], cnt0, pad)

// Hand-placed waitcnt + mandatory scheduling fence (guide rule #18).
#define WAITVM(N) do { asm volatile("s_waitcnt vmcnt(" #N ")" ::: "memory"); \
                       __builtin_amdgcn_sched_barrier(0); } while (0)

typedef __attribute__((address_space(3))) unsigned int lds_u32;
typedef const __attribute__((address_space(1))) unsigned int glb_u32;

// One call stages 1 KB: HW writes each lane's 16B at (dst + lane*16).
// src is PER-LANE (must already include lane*16); dst is wave-uniform.
__device__ __forceinline__ void dma1k(const float* src, const float4* dst) {
    __builtin_amdgcn_global_load_lds((glb_u32*)(uintptr_t)src,
                                     (lds_u32*)(unsigned int)(uintptr_t)dst,
                                     16, 0, 0);
}

// Stage one full row (4 modalities x 2KB) = 8 DMA ops = vmcnt +8.
__device__ __forceinline__ void dma_row(const float* const X[4], unsigned r,
                                        const float4* dstbase, int lane) {
    #pragma unroll
    for (int m = 0; m < 4; ++m) {
        const float* src = X[m] + (size_t)r * D_DIM + lane * 4;
        dma1k(src,       dstbase + m * 128);
        dma1k(src + 256, dstbase + m * 128 + 64);
    }
}

__device__ __forceinline__ float dot4(float4 a, float4 b) {
    return a.x * b.x + a.y * b.y + a.z * b.z + a.w * b.w;
}

// Reduce 8 independent per-lane values over 64 lanes with 11 shuffles.
// Lane group g=(lane>>3) ends holding the total of value j=g.
__device__ __forceinline__ float fold_reduce8(const float v[8], int lane) {
    float w[4];
    #pragma unroll
    for (int i = 0; i < 4; ++i) {
        float send = (lane & 32) ? v[i] : v[i + 4];
        float rcv  = __shfl_xor(send, 32);
        w[i] = ((lane & 32) ? v[i + 4] : v[i]) + rcv;
    }
    float u[2];
    #pragma unroll
    for (int i = 0; i < 2; ++i) {
        float send = (lane & 16) ? w[i] : w[i + 2];
        float rcv  = __shfl_xor(send, 16);
        u[i] = ((lane & 16) ? w[i + 2] : w[i]) + rcv;
    }
    float t;
    {
        float send = (lane & 8) ? u[0] : u[1];
        float rcv  = __shfl_xor(send, 8);
        t = ((lane & 8) ? u[1] : u[0]) + rcv;
    }
    t += __shfl_xor(t, 4);
    t += __shfl_xor(t, 2);
    t += __shfl_xor(t, 1);
    return t;
}

// ------------------------------------------------- early-exit anchor finder
__global__ void find_anchor_kernel(const int* __restrict__ label, Ws* ws) {
    __shared__ unsigned smin[4];
    __shared__ unsigned sres;
    const int t = threadIdx.x, lane = t & 63, wid = t >> 6;
    for (unsigned base = 0; base < B_ROWS; base += 1024) {
        int4 v = ((const int4*)label)[(base >> 2) + t];
        unsigned idx = base + (unsigned)t * 4;
        unsigned my = 0xFFFFFFFFu;
        if (v.w == 0) my = idx + 3;
        if (v.z == 0) my = idx + 2;
        if (v.y == 0) my = idx + 1;
        if (v.x == 0) my = idx;
        #pragma unroll
        for (int off = 32; off; off >>= 1) {
            unsigned o = (unsigned)__shfl_xor((int)my, off);
            my = my < o ? my : o;
        }
        if (lane == 0) smin[wid] = my;
        __syncthreads();
        if (t == 0) {
            unsigned m = min(min(smin[0], smin[1]), min(smin[2], smin[3]));
            sres = m;
            if (m != 0xFFFFFFFFu) ws->anchor_idx = m;
        }
        __syncthreads();
        if (sres != 0xFFFFFFFFu) return;   // uniform exit (typically 1st chunk)
        __syncthreads();
    }
}

// ------------------------------------------------- main pass (+ fused tail)
// Per-wave DMA streaming: global_load_lds double-buffer, 2 rows (16 KB) in
// flight per wave at all times, zero destination VGPRs, hand-placed vmcnt.
// Main loop is byte-identical to the round-6 kernel (best measured).
__launch_bounds__(TPB, 2)
__global__ void cos_accum_kernel(const int* __restrict__ label,
                                 const float* __restrict__ p_t,
                                 const float* __restrict__ p_a,
                                 const float* __restrict__ s_t,
                                 const float* __restrict__ s_a,
                                 Ws* ws,
                                 float* __restrict__ partials,
                                 float* __restrict__ out) {
    const float* X[4] = {p_t, p_a, s_t, s_a};
    __shared__ float4 buf[WPB][2][512];   // 4 waves x 2 bufs x 8 KB = 64 KB
    __shared__ float  red[WPB][12];
    __shared__ float  fin[256];
    __shared__ float  colsum[9];
    __shared__ int    slast;

    const unsigned aidx = ws->anchor_idx;
    const int lane = threadIdx.x & 63;
    const int wid  = __builtin_amdgcn_readfirstlane((int)(threadIdx.x >> 6));
    const unsigned gwave = (unsigned)blockIdx.x * WPB + (unsigned)wid;

    // ---- prologue: anchor reg-loads FIRST (oldest vmcnt slots) ----
    float4 an[8];
    #pragma unroll
    for (int m = 0; m < 4; ++m) {
        const float4* A = (const float4*)(X[m] + (size_t)aidx * D_DIM);
        an[2 * m]     = A[lane];
        an[2 * m + 1] = A[64 + lane];
    }
    // then the first two row-DMAs (16 ops outstanding)
    dma_row(X, gwave,          &buf[wid][0][0], lane);
    dma_row(X, gwave + NWAVES, &buf[wid][1][0], lane);

    // labels: wave-uniform scalar loads (lgkm path, vmcnt untouched)
    int lab[RPW];
    #pragma unroll
    for (int k = 0; k < RPW; ++k)
        lab[k] = label[__builtin_amdgcn_readfirstlane((int)(gwave + (unsigned)k * NWAVES))];
    int myzero = 0;
    #pragma unroll
    for (int k = 0; k < RPW; ++k) myzero += (lab[k] == 0);

    // anchor inverse-norms: lanes 0,8,16,24 hold 1/||a_m|| for m=lane>>3
    float inv_mine;
    {
        float va[8];
        #pragma unroll
        for (int m = 0; m < 4; ++m) {
            va[m]     = dot4(an[2 * m], an[2 * m]) + dot4(an[2 * m + 1], an[2 * m + 1]);
            va[m + 4] = 0.f;
        }
        inv_mine = rsqrtf(fold_reduce8(va, lane));
    }

    float posAcc = 0.f, negAcc = 0.f;

    #pragma unroll
    for (int k = 0; k < RPW; ++k) {
        if (k < RPW - 1) { WAITVM(8); }   // row k landed; row k+1 still in flight
        else            { WAITVM(0); }    // final row

        const unsigned r = gwave + (unsigned)k * NWAVES;
        const float4* bp = &buf[wid][k & 1][0];

        float4 x[8];
        #pragma unroll
        for (int m = 0; m < 4; ++m) {
            x[2 * m]     = bp[m * 128 + lane];
            x[2 * m + 1] = bp[m * 128 + 64 + lane];
        }
        float v[8];
        #pragma unroll
        for (int m = 0; m < 4; ++m) {
            v[m]     = dot4(x[2 * m], an[2 * m]) + dot4(x[2 * m + 1], an[2 * m + 1]);
            v[m + 4] = dot4(x[2 * m], x[2 * m])  + dot4(x[2 * m + 1], x[2 * m + 1]);
        }

        // buffer k&1 fully consumed into v[] -> safe to re-issue DMA into it.
        if (k + 2 < RPW)
            dma_row(X, gwave + (unsigned)(k + 2) * NWAVES, &buf[wid][k & 1][0], lane);

        float t     = fold_reduce8(v, lane);
        float other = __shfl_xor(t, 32);       // lane 8m (<32): t=dot_m, other=nrm_m
        if (((lane & 39) == 0) && (r != aidx)) {   // lanes 0,8,16,24
            float c = t * rsqrtf(other) * inv_mine;
            if (lab[k] == 0) posAcc += c; else negAcc += c;
        }
    }

    // ---- block reduce -> private partials slot ----
    if ((lane & 39) == 0) {
        int m = lane >> 3;
        red[wid][m]     = posAcc;
        red[wid][4 + m] = negAcc;
    }
    if (lane == 0) red[wid][8] = (float)myzero;
    __syncthreads();
    if (threadIdx.x < 9) {
        int j = threadIdx.x;
        partials[blockIdx.x * 12 + j] = red[0][j] + red[1][j] + red[2][j] + red[3][j];
    }

    // ---- last-block finalize (device-scope protocol, same as r7: verified) ----
    __threadfence();
    __syncthreads();
    if (threadIdx.x == 0) {
        int old = atomicAdd(&ws->done, 1);
        slast = (old == (int)(NBLOCKS - 2));
    }
    __syncthreads();
    if (!slast) return;

    {
        const int t = threadIdx.x;
        int j = t >> 4;          // 0..15
        int g = t & 15;
        float s = 0.f;
        if (j < 9) {
            for (int r2 = g; r2 < NBLOCKS; r2 += 16)
                s += __hip_atomic_load(&partials[r2 * 12 + j],
                                       __ATOMIC_RELAXED, __HIP_MEMORY_SCOPE_AGENT);
        }
        fin[t] = s;
        __syncthreads();
        if (t < 9) {
            float tot = 0.f;
            #pragma unroll
            for (int g2 = 0; g2 < 16; ++g2) tot += fin[t * 16 + g2];
            colsum[t] = tot;
        }
        __syncthreads();
        if (t == 0) {
            float cnt0    = colsum[8];
            float pos_cnt = cnt0 - 1.0f;
            float neg_cnt = (float)B_ROWS - cnt0;
            float total = 0.f;
            #pragma unroll
            for (int m = 0; m < 4; ++m) {
                float ps = (pos_cnt > 0.f) ? colsum[m]     / fmaxf(pos_cnt, 1.f) : 0.f;
                float ns = (neg_cnt > 0.f) ? colsum[4 + m] / fmaxf(neg_cnt, 1.f) : 0.f;
                total += 2.0f - ps + ns;
            }
            out[0] = total * 0.25f;
        }
    }
}

extern "C" void kernel_launch(void* const* d_in, const int* in_sizes, int n_in,
                              void* d_out, int out_size, void* d_ws, size_t ws_size,
                              hipStream_t stream) {
    const int*   label = (const int*)  d_in[0];
    const float* p_t   = (const float*)d_in[1];
    const float* p_a   = (const float*)d_in[2];
    const float* s_t   = (const float*)d_in[3];
    const float* s_a   = (const float*)d_in[4];
    Ws* ws = (Ws*)d_ws;
    float* partials = (float*)d_ws + 64;   // 256B past header

    // anchor_idx <- 0xFFFFFFFF (overwritten by finder) ; done <- -1
    hipMemsetAsync(d_ws, 0xFF, 8, stream);

    find_anchor_kernel <<<1,       TPB, 0, stream>>>(label, ws);
    cos_accum_kernel   <<<NBLOCKS, TPB, 0, stream>>>(label, p_t, p_a, s_t, s_a,
                                                     ws, partials, (float*)d_out);
}

// Round 9
// 63.237 us; speedup vs baseline: 1.7585x; 1.7585x over previous
//
#include <hip/hip_runtime.h>
#include <cstdint>

#define B_ROWS   32768
#define D_DIM    512
#define NBLOCKS  512             // 2 blocks/CU exactly (LDS-capped), all resident
#define TPB      256             // 4 waves per block
#define WPB      (TPB / 64)
#define NWAVES   (NBLOCKS * WPB)          // 2048
#define RPW      (B_ROWS / NWAVES)        // 16 rows per wave, exact

struct Ws {
    unsigned anchor_idx;   // written unconditionally by find_anchor
};
// partials at (float*)d_ws + 64 : [NBLOCKS][12] (pos[4], neg[4], cnt0, pad)

// Hand-placed waitcnt + mandatory scheduling fence (guide rule #18).
#define WAITVM(N) do { asm volatile("s_waitcnt vmcnt(" #N ")" ::: "memory"); \
                       __builtin_amdgcn_sched_barrier(0); } while (0)

typedef __attribute__((address_space(3))) unsigned int lds_u32;
typedef const __attribute__((address_space(1))) unsigned int glb_u32;

// One call stages 1 KB: HW writes each lane's 16B at (dst + lane*16).
// src is PER-LANE (must already include lane*16); dst is wave-uniform.
__device__ __forceinline__ void dma1k(const float* src, const float4* dst) {
    __builtin_amdgcn_global_load_lds((glb_u32*)(uintptr_t)src,
                                     (lds_u32*)(unsigned int)(uintptr_t)dst,
                                     16, 0, 0);
}

// Stage one full row (4 modalities x 2KB) = 8 DMA ops = vmcnt +8.
__device__ __forceinline__ void dma_row(const float* const X[4], unsigned r,
                                        const float4* dstbase, int lane) {
    #pragma unroll
    for (int m = 0; m < 4; ++m) {
        const float* src = X[m] + (size_t)r * D_DIM + lane * 4;
        dma1k(src,       dstbase + m * 128);
        dma1k(src + 256, dstbase + m * 128 + 64);
    }
}

__device__ __forceinline__ float dot4(float4 a, float4 b) {
    return a.x * b.x + a.y * b.y + a.z * b.z + a.w * b.w;
}

// Reduce 8 independent per-lane values over 64 lanes with 11 shuffles.
// Lane group g=(lane>>3) ends holding the total of value j=g.
__device__ __forceinline__ float fold_reduce8(const float v[8], int lane) {
    float w[4];
    #pragma unroll
    for (int i = 0; i < 4; ++i) {
        float send = (lane & 32) ? v[i] : v[i + 4];
        float rcv  = __shfl_xor(send, 32);
        w[i] = ((lane & 32) ? v[i + 4] : v[i]) + rcv;
    }
    float u[2];
    #pragma unroll
    for (int i = 0; i < 2; ++i) {
        float send = (lane & 16) ? w[i] : w[i + 2];
        float rcv  = __shfl_xor(send, 16);
        u[i] = ((lane & 16) ? w[i + 2] : w[i]) + rcv;
    }
    float t;
    {
        float send = (lane & 8) ? u[0] : u[1];
        float rcv  = __shfl_xor(send, 8);
        t = ((lane & 8) ? u[1] : u[0]) + rcv;
    }
    t += __shfl_xor(t, 4);
    t += __shfl_xor(t, 2);
    t += __shfl_xor(t, 1);
    return t;
}

// ------------------------------------------------- early-exit anchor finder
__global__ void find_anchor_kernel(const int* __restrict__ label, Ws* ws) {
    __shared__ unsigned smin[4];
    __shared__ unsigned sres;
    const int t = threadIdx.x, lane = t & 63, wid = t >> 6;
    for (unsigned base = 0; base < B_ROWS; base += 1024) {
        int4 v = ((const int4*)label)[(base >> 2) + t];
        unsigned idx = base + (unsigned)t * 4;
        unsigned my = 0xFFFFFFFFu;
        if (v.w == 0) my = idx + 3;
        if (v.z == 0) my = idx + 2;
        if (v.y == 0) my = idx + 1;
        if (v.x == 0) my = idx;
        #pragma unroll
        for (int off = 32; off; off >>= 1) {
            unsigned o = (unsigned)__shfl_xor((int)my, off);
            my = my < o ? my : o;
        }
        if (lane == 0) smin[wid] = my;
        __syncthreads();
        if (t == 0) {
            unsigned m = min(min(smin[0], smin[1]), min(smin[2], smin[3]));
            sres = m;
            if (m != 0xFFFFFFFFu) ws->anchor_idx = m;
        }
        __syncthreads();
        if (sres != 0xFFFFFFFFu) return;   // uniform exit (typically 1st chunk)
        __syncthreads();
    }
}

// ------------------------------------------------- main pass (r6 structure)
// Per-wave DMA streaming: global_load_lds double-buffer, 2 rows (16 KB) in
// flight per wave, zero destination VGPRs, hand-placed vmcnt. NO fence, NO
// atomics, NO fused tail -- those cost 2x in r8 (per-block agent fence = L2
// invalidate mid-stream on every XCD).
__launch_bounds__(TPB, 2)
__global__ void cos_accum_kernel(const int* __restrict__ label,
                                 const float* __restrict__ p_t,
                                 const float* __restrict__ p_a,
                                 const float* __restrict__ s_t,
                                 const float* __restrict__ s_a,
                                 const Ws* __restrict__ ws,
                                 float* __restrict__ partials) {
    const float* X[4] = {p_t, p_a, s_t, s_a};
    __shared__ float4 buf[WPB][2][512];   // 4 waves x 2 bufs x 8 KB = 64 KB
    __shared__ float  red[WPB][12];

    const unsigned aidx = ws->anchor_idx;
    const int lane = threadIdx.x & 63;
    const int wid  = __builtin_amdgcn_readfirstlane((int)(threadIdx.x >> 6));
    const unsigned gwave = (unsigned)blockIdx.x * WPB + (unsigned)wid;

    // ---- prologue: anchor reg-loads FIRST (oldest vmcnt slots) ----
    float4 an[8];
    #pragma unroll
    for (int m = 0; m < 4; ++m) {
        const float4* A = (const float4*)(X[m] + (size_t)aidx * D_DIM);
        an[2 * m]     = A[lane];
        an[2 * m + 1] = A[64 + lane];
    }
    // then the first two row-DMAs (16 ops outstanding)
    dma_row(X, gwave,          &buf[wid][0][0], lane);
    dma_row(X, gwave + NWAVES, &buf[wid][1][0], lane);

    // labels: wave-uniform scalar loads (lgkm path, vmcnt untouched)
    int lab[RPW];
    #pragma unroll
    for (int k = 0; k < RPW; ++k)
        lab[k] = label[gwave + (unsigned)k * NWAVES];
    int myzero = 0;
    #pragma unroll
    for (int k = 0; k < RPW; ++k) myzero += (lab[k] == 0);

    // anchor inverse-norms: lanes 0,8,16,24 hold 1/||a_m|| for m=lane>>3
    float inv_mine;
    {
        float va[8];
        #pragma unroll
        for (int m = 0; m < 4; ++m) {
            va[m]     = dot4(an[2 * m], an[2 * m]) + dot4(an[2 * m + 1], an[2 * m + 1]);
            va[m + 4] = 0.f;
        }
        inv_mine = rsqrtf(fold_reduce8(va, lane));
    }

    float posAcc = 0.f, negAcc = 0.f;

    #pragma unroll
    for (int k = 0; k < RPW; ++k) {
        if (k < RPW - 1) { WAITVM(8); }   // row k landed; row k+1 still in flight
        else            { WAITVM(0); }    // final row

        const unsigned r = gwave + (unsigned)k * NWAVES;
        const float4* bp = &buf[wid][k & 1][0];

        float4 x[8];
        #pragma unroll
        for (int m = 0; m < 4; ++m) {
            x[2 * m]     = bp[m * 128 + lane];
            x[2 * m + 1] = bp[m * 128 + 64 + lane];
        }
        float v[8];
        #pragma unroll
        for (int m = 0; m < 4; ++m) {
            v[m]     = dot4(x[2 * m], an[2 * m]) + dot4(x[2 * m + 1], an[2 * m + 1]);
            v[m + 4] = dot4(x[2 * m], x[2 * m])  + dot4(x[2 * m + 1], x[2 * m + 1]);
        }

        // buffer k&1 fully consumed into v[] -> safe to re-issue DMA into it.
        if (k + 2 < RPW)
            dma_row(X, gwave + (unsigned)(k + 2) * NWAVES, &buf[wid][k & 1][0], lane);

        float t     = fold_reduce8(v, lane);
        float other = __shfl_xor(t, 32);       // lane 8m (<32): t=dot_m, other=nrm_m
        if (((lane & 39) == 0) && (r != aidx)) {   // lanes 0,8,16,24
            float c = t * rsqrtf(other) * inv_mine;
            if (lab[k] == 0) posAcc += c; else negAcc += c;
        }
    }

    // ---- block reduce -> private partials slot (plain stores; visibility
    // across dispatch boundary is guaranteed by stream ordering) ----
    if ((lane & 39) == 0) {
        int m = lane >> 3;
        red[wid][m]     = posAcc;
        red[wid][4 + m] = negAcc;
    }
    if (lane == 0) red[wid][8] = (float)myzero;
    __syncthreads();
    if (threadIdx.x < 9) {
        int j = threadIdx.x;
        partials[blockIdx.x * 12 + j] = red[0][j] + red[1][j] + red[2][j] + red[3][j];
    }
}

// ---------------------------------------------------------------- finalize
__global__ void finalize_kernel(const float* __restrict__ partials,
                                float* __restrict__ out) {
    __shared__ float fin[256];
    __shared__ float colsum[9];
    const int t = threadIdx.x;
    int j = t >> 4;          // 0..15
    int g = t & 15;
    float s = 0.f;
    if (j < 9) {
        for (int r2 = g; r2 < NBLOCKS; r2 += 16)
            s += partials[r2 * 12 + j];
    }
    fin[t] = s;
    __syncthreads();
    if (t < 9) {
        float tot = 0.f;
        #pragma unroll
        for (int g2 = 0; g2 < 16; ++g2) tot += fin[t * 16 + g2];
        colsum[t] = tot;
    }
    __syncthreads();
    if (t == 0) {
        float cnt0    = colsum[8];
        float pos_cnt = cnt0 - 1.0f;
        float neg_cnt = (float)B_ROWS - cnt0;
        float total = 0.f;
        #pragma unroll
        for (int m = 0; m < 4; ++m) {
            float ps = (pos_cnt > 0.f) ? colsum[m]     / fmaxf(pos_cnt, 1.f) : 0.f;
            float ns = (neg_cnt > 0.f) ? colsum[4 + m] / fmaxf(neg_cnt, 1.f) : 0.f;
            total += 2.0f - ps + ns;
        }
        out[0] = total * 0.25f;
    }
}

extern "C" void kernel_launch(void* const* d_in, const int* in_sizes, int n_in,
                              void* d_out, int out_size, void* d_ws, size_t ws_size,
                              hipStream_t stream) {
    const int*   label = (const int*)  d_in[0];
    const float* p_t   = (const float*)d_in[1];
    const float* p_a   = (const float*)d_in[2];
    const float* s_t   = (const float*)d_in[3];
    const float* s_a   = (const float*)d_in[4];
    Ws* ws = (Ws*)d_ws;
    float* partials = (float*)d_ws + 64;   // 256B past header

    // no memset needed: find_anchor always writes anchor_idx (class 0
    // guaranteed present), partials columns 0..8 fully written every launch.
    find_anchor_kernel <<<1,       TPB, 0, stream>>>(label, ws);
    cos_accum_kernel   <<<NBLOCKS, TPB, 0, stream>>>(label, p_t, p_a, s_t, s_a,
                                                     ws, partials);
    finalize_kernel    <<<1,       TPB, 0, stream>>>(partials, (float*)d_out);
}